// Round 1
// baseline (398.507 us; speedup 1.0000x reference)
//
#include <hip/hip_runtime.h>
#include <math.h>

#define LRELU_ALPHA 0.2f
#define NEG_BIG -9000000000000000.0f

// -------------------------------------------------------------------------
// Kernel 1: attention weights. One wave per (graph i, node n), i in {0,1},
// n in [0,2048). Computes chunk = Wh[i, n, i*6:(i+1)*6, :] (6x64, fp32),
// s1 = chunk@a1, s2 = chunk@a2 (wave butterfly reductions),
// e = leaky_relu(s1[p]+s2[q]), mask by adj[i], softmax over q.
// Stores att[(i*2048+n)*36 + p*6 + q] into workspace.
// -------------------------------------------------------------------------
__global__ __launch_bounds__(256) void gat_att_kernel(
    const float* __restrict__ h, const int* __restrict__ adj,
    const float* __restrict__ W, const float* __restrict__ a,
    float* __restrict__ att_ws)
{
    __shared__ float sm[4 * 6 * 128];   // 12 KB: 4 waves x 6 rows x 128
    const int warp = threadIdx.x >> 6;
    const int lane = threadIdx.x & 63;
    const int iw = blockIdx.x * 4 + warp;   // 0..4095
    const int gi = iw >> 11;                // graph index 0/1
    const int n  = iw & 2047;

    // h rows for batch gi, k = gi*6 .. gi*6+5
    const float* hp = h + ((size_t)(gi * 2048 + n) * 12 + (size_t)gi * 6) * 128;
    float* smw = sm + warp * 768;

    // stage 6x128 floats (3 KB) into LDS, 16B per lane per step
#pragma unroll
    for (int j = 0; j < 3; ++j) {
        *(float4*)(smw + j * 256 + lane * 4) =
            *(const float4*)(hp + j * 256 + lane * 4);
    }
    __syncthreads();

    const int f = lane;
    float acc[6];
#pragma unroll
    for (int q = 0; q < 6; ++q) acc[q] = 0.f;

    const float* Wp = W + f;
    for (int c = 0; c < 128; c += 4) {
        float w0 = Wp[(c + 0) * 64];
        float w1 = Wp[(c + 1) * 64];
        float w2 = Wp[(c + 2) * 64];
        float w3 = Wp[(c + 3) * 64];
#pragma unroll
        for (int q = 0; q < 6; ++q) {
            float4 hv = *(const float4*)(smw + q * 128 + c);  // uniform addr: broadcast
            acc[q] = fmaf(hv.x, w0, fmaf(hv.y, w1, fmaf(hv.z, w2, fmaf(hv.w, w3, acc[q]))));
        }
    }

    // s1[q] = sum_f acc[q]*a1[f]; s2[q] = sum_f acc[q]*a2[f]
    const float a1v = a[gi * 128 + f];
    const float a2v = a[gi * 128 + 64 + f];
    float s1[6], s2[6];
#pragma unroll
    for (int q = 0; q < 6; ++q) {
        float t1 = acc[q] * a1v;
        float t2 = acc[q] * a2v;
#pragma unroll
        for (int off = 32; off > 0; off >>= 1) {
            t1 += __shfl_xor(t1, off, 64);
            t2 += __shfl_xor(t2, off, 64);
        }
        s1[q] = t1;   // all lanes hold full sums
        s2[q] = t2;
    }

    if (lane < 6) {
        const int p = lane;
        // select s1[p] without dynamic register indexing
        float s1p = s1[0];
#pragma unroll
        for (int q = 1; q < 6; ++q) { if (p == q) s1p = s1[q]; }

        float row[6];
        float mx = -3.0e38f;
#pragma unroll
        for (int q = 0; q < 6; ++q) {
            float e = s1p + s2[q];
            e = (e > 0.f) ? e : (LRELU_ALPHA * e);
            const int ad = adj[gi * 36 + p * 6 + q];
            const float m = (ad > 0) ? e : NEG_BIG;
            row[q] = m;
            mx = fmaxf(mx, m);
        }
        float sum = 0.f;
#pragma unroll
        for (int q = 0; q < 6; ++q) {
            row[q] = expf(row[q] - mx);
            sum += row[q];
        }
        const float inv = 1.f / sum;
        float* op = att_ws + (size_t)iw * 36 + p * 6;
#pragma unroll
        for (int q = 0; q < 6; ++q) op[q] = row[q] * inv;
    }
}

// -------------------------------------------------------------------------
// Kernel 2: main pass. One wave per (b,n), 4 waves per block.
// Stage h[b,n,0:12,0:128] (6 KB) in LDS; lane = output column f.
// acc[k] = sum_c h[k][c]*W[c][f]  (12 fp32 accumulators)
// then out[b,n,i*6+p,f] = elu( sum_q att[i,n,p,q] * acc[i*6+q] ).
// -------------------------------------------------------------------------
__global__ __launch_bounds__(256) void gat_main_kernel(
    const float* __restrict__ h, const float* __restrict__ W,
    const float* __restrict__ att_ws, float* __restrict__ out)
{
    __shared__ float sm[4 * 12 * 128];  // 24 KB
    const int warp = threadIdx.x >> 6;
    const int lane = threadIdx.x & 63;
    const int bn = blockIdx.x * 4 + warp;   // 0..32767  (b = bn>>11, n = bn&2047)
    const int n = bn & 2047;

    const float* hp = h + (size_t)bn * 1536;
    float* smw = sm + warp * 1536;

#pragma unroll
    for (int j = 0; j < 6; ++j) {
        *(float4*)(smw + j * 256 + lane * 4) =
            *(const float4*)(hp + j * 256 + lane * 4);
    }
    __syncthreads();

    const int f = lane;
    float acc[12];
#pragma unroll
    for (int k = 0; k < 12; ++k) acc[k] = 0.f;

    const float* Wp = W + f;
    for (int c = 0; c < 128; c += 4) {
        float w0 = Wp[(c + 0) * 64];
        float w1 = Wp[(c + 1) * 64];
        float w2 = Wp[(c + 2) * 64];
        float w3 = Wp[(c + 3) * 64];
#pragma unroll
        for (int k = 0; k < 12; ++k) {
            float4 hv = *(const float4*)(smw + k * 128 + c);  // uniform addr: broadcast
            acc[k] = fmaf(hv.x, w0, fmaf(hv.y, w1, fmaf(hv.z, w2, fmaf(hv.w, w3, acc[k]))));
        }
    }

    // fused attention combine + elu + store
    float* op = out + (size_t)bn * 768 + f;
    const float* aw0 = att_ws + (size_t)n * 36;             // graph 0
    const float* aw1 = att_ws + (size_t)(2048 + n) * 36;    // graph 1
#pragma unroll
    for (int gi = 0; gi < 2; ++gi) {
        const float* awp = gi ? aw1 : aw0;
#pragma unroll
        for (int p = 0; p < 6; ++p) {
            float v = 0.f;
#pragma unroll
            for (int q = 0; q < 6; ++q)
                v = fmaf(awp[p * 6 + q], acc[gi * 6 + q], v);
            v = (v > 0.f) ? v : (expf(v) - 1.f);   // elu, alpha=1
            op[(gi * 6 + p) * 64] = v;
        }
    }
}

extern "C" void kernel_launch(void* const* d_in, const int* in_sizes, int n_in,
                              void* d_out, int out_size, void* d_ws, size_t ws_size,
                              hipStream_t stream) {
    const float* h   = (const float*)d_in[0];   // (16,2048,12,128) fp32
    const int*   adj = (const int*)d_in[1];     // (2,6,6) int32
    const float* W   = (const float*)d_in[2];   // (128,64) fp32
    const float* a   = (const float*)d_in[3];   // (2,128,1) fp32
    float* out = (float*)d_out;                 // (16,2048,12,64) fp32
    float* att_ws = (float*)d_ws;               // 2*2048*36 floats = 1.18 MB

    // 4096 (i,n) waves -> 1024 blocks of 256
    hipLaunchKernelGGL(gat_att_kernel, dim3(1024), dim3(256), 0, stream,
                       h, adj, W, a, att_ws);
    // 32768 (b,n) waves -> 8192 blocks of 256
    hipLaunchKernelGGL(gat_main_kernel, dim3(8192), dim3(256), 0, stream,
                       h, W, att_ws, out);
}

// Round 2
// 340.119 us; speedup vs baseline: 1.1717x; 1.1717x over previous
//
#include <hip/hip_runtime.h>
#include <math.h>

#define LRELU_ALPHA 0.2f
#define NEG_BIG -9000000000000000.0f

typedef __attribute__((ext_vector_type(8))) short bf16x8;
typedef __attribute__((ext_vector_type(4))) float f32x4;

static __device__ inline unsigned short f2bf(float x) {
    unsigned int u = __float_as_uint(x);
    unsigned int r = (u + 0x7FFFu + ((u >> 16) & 1u)) >> 16;   // RNE
    return (unsigned short)r;
}

// -------------------------------------------------------------------------
// Kernel 1: attention weights (fp32, unchanged from R1 — small & accurate).
// One wave per (graph i, node n). chunk = Wh[i,n,i*6:(i+1)*6,:] (6x64),
// s1/s2 via 64-lane butterfly, leaky_relu + adj mask + softmax.
// att_ws[(i*2048+n)*36 + p*6 + q].
// -------------------------------------------------------------------------
__global__ __launch_bounds__(256) void gat_att_kernel(
    const float* __restrict__ h, const int* __restrict__ adj,
    const float* __restrict__ W, const float* __restrict__ a,
    float* __restrict__ att_ws)
{
    __shared__ float sm[4 * 6 * 128];
    const int warp = threadIdx.x >> 6;
    const int lane = threadIdx.x & 63;
    const int iw = blockIdx.x * 4 + warp;   // 0..4095
    const int gi = iw >> 11;
    const int n  = iw & 2047;

    const float* hp = h + ((size_t)(gi * 2048 + n) * 12 + (size_t)gi * 6) * 128;
    float* smw = sm + warp * 768;

#pragma unroll
    for (int j = 0; j < 3; ++j)
        *(float4*)(smw + j * 256 + lane * 4) = *(const float4*)(hp + j * 256 + lane * 4);
    __syncthreads();

    const int f = lane;
    float acc[6];
#pragma unroll
    for (int q = 0; q < 6; ++q) acc[q] = 0.f;

    const float* Wp = W + f;
    for (int c = 0; c < 128; c += 4) {
        float w0 = Wp[(c + 0) * 64];
        float w1 = Wp[(c + 1) * 64];
        float w2 = Wp[(c + 2) * 64];
        float w3 = Wp[(c + 3) * 64];
#pragma unroll
        for (int q = 0; q < 6; ++q) {
            float4 hv = *(const float4*)(smw + q * 128 + c);
            acc[q] = fmaf(hv.x, w0, fmaf(hv.y, w1, fmaf(hv.z, w2, fmaf(hv.w, w3, acc[q]))));
        }
    }

    const float a1v = a[gi * 128 + f];
    const float a2v = a[gi * 128 + 64 + f];
    float s1[6], s2[6];
#pragma unroll
    for (int q = 0; q < 6; ++q) {
        float t1 = acc[q] * a1v;
        float t2 = acc[q] * a2v;
#pragma unroll
        for (int off = 32; off > 0; off >>= 1) {
            t1 += __shfl_xor(t1, off, 64);
            t2 += __shfl_xor(t2, off, 64);
        }
        s1[q] = t1;
        s2[q] = t2;
    }

    if (lane < 6) {
        const int p = lane;
        float s1p = s1[0];
#pragma unroll
        for (int q = 1; q < 6; ++q) { if (p == q) s1p = s1[q]; }

        float row[6];
        float mx = -3.0e38f;
#pragma unroll
        for (int q = 0; q < 6; ++q) {
            float e = s1p + s2[q];
            e = (e > 0.f) ? e : (LRELU_ALPHA * e);
            const int ad = adj[gi * 36 + p * 6 + q];
            const float m = (ad > 0) ? e : NEG_BIG;
            row[q] = m;
            mx = fmaxf(mx, m);
        }
        float sum = 0.f;
#pragma unroll
        for (int q = 0; q < 6; ++q) {
            row[q] = expf(row[q] - mx);
            sum += row[q];
        }
        const float inv = 1.f / sum;
        float* op = att_ws + (size_t)iw * 36 + p * 6;
#pragma unroll
        for (int q = 0; q < 6; ++q) op[q] = row[q] * inv;
    }
}

// -------------------------------------------------------------------------
// Kernel 2: out = elu( (Att @ h) @ W ) via bf16 MFMA.
// Wave = 4 (b,n) groups = 48 rows. Phase 1: fp32 att-combine of h rows in
// registers (half-wave per bn, lane covers 4 cols), bf16-pack into per-wave
// LDS P[48][128]. Phase 2: 3 M-tiles x 4 N-tiles x 4 K-steps of
// mfma_f32_16x16x32_bf16 against W^T staged bf16 in LDS. Epilogue: elu.
// -------------------------------------------------------------------------
__global__ __launch_bounds__(256) void gat_main_mfma(
    const float* __restrict__ h, const float* __restrict__ W,
    const float* __restrict__ att_ws, float* __restrict__ out)
{
    __shared__ __align__(16) short lds[32768];     // 64 KB exactly
    short* Wt = lds;                               // [64 n][128 k] bf16
    const int tid  = threadIdx.x;
    const int warp = tid >> 6;
    const int lane = tid & 63;
    short* Pw = lds + 8192 + warp * 6144;          // [48 rows][128 k] bf16

    // stage W transposed -> bf16 (once per block)
    for (int idx = tid; idx < 8192; idx += 256) {
        const int k = idx >> 6, n = idx & 63;
        Wt[n * 128 + k] = (short)f2bf(W[idx]);
    }

    const int wave_id = blockIdx.x * 4 + warp;
    const int bn0 = wave_id * 4;                   // 4 consecutive (b,n); same b (4|2048)
    const int half = lane >> 5;                    // half-wave -> which bn of the pair
    const int li   = lane & 31;                    // covers cols 4*li..4*li+3

    for (int pair = 0; pair < 2; ++pair) {
        const int bno = pair * 2 + half;           // 0..3
        const int bn  = bn0 + bno;
        const int n   = bn & 2047;

        const float* hb = h + (size_t)bn * 1536 + li * 4;
        float4 hv[12];
#pragma unroll
        for (int r = 0; r < 12; ++r)
            hv[r] = *(const float4*)(hb + r * 128);   // 12 independent 1KB/wave loads

#pragma unroll
        for (int gi = 0; gi < 2; ++gi) {
            const float4* ap = (const float4*)(att_ws + (size_t)(gi * 2048 + n) * 36);
            float4 av[9];
#pragma unroll
            for (int j = 0; j < 9; ++j) av[j] = ap[j];
            float attv[36];
#pragma unroll
            for (int j = 0; j < 9; ++j) {
                attv[j * 4 + 0] = av[j].x; attv[j * 4 + 1] = av[j].y;
                attv[j * 4 + 2] = av[j].z; attv[j * 4 + 3] = av[j].w;
            }
#pragma unroll
            for (int p = 0; p < 6; ++p) {
                float ax = 0.f, ay = 0.f, az = 0.f, aw = 0.f;
#pragma unroll
                for (int q = 0; q < 6; ++q) {
                    const float apq = attv[p * 6 + q];
                    const float4 hq = hv[gi * 6 + q];
                    ax = fmaf(apq, hq.x, ax);
                    ay = fmaf(apq, hq.y, ay);
                    az = fmaf(apq, hq.z, az);
                    aw = fmaf(apq, hq.w, aw);
                }
                const int row = bno * 12 + gi * 6 + p;   // local row 0..47
                ushort4 pk;
                pk.x = f2bf(ax); pk.y = f2bf(ay);
                pk.z = f2bf(az); pk.w = f2bf(aw);
                *(ushort4*)(Pw + row * 128 + li * 4) = pk;  // 8B write, ~4-way: free-ish
            }
        }
    }
    __syncthreads();   // covers both Wt (cross-wave) and P (own-wave) visibility

    const int col  = lane & 15;
    const int quad = lane >> 4;
    f32x4 acc[3][4];
#pragma unroll
    for (int mt = 0; mt < 3; ++mt)
#pragma unroll
        for (int nt = 0; nt < 4; ++nt)
            acc[mt][nt] = (f32x4){0.f, 0.f, 0.f, 0.f};

#pragma unroll
    for (int ks = 0; ks < 4; ++ks) {
        bf16x8 bfr[4];
#pragma unroll
        for (int nt = 0; nt < 4; ++nt)
            bfr[nt] = *(const bf16x8*)(Wt + (nt * 16 + col) * 128 + ks * 32 + quad * 8);
#pragma unroll
        for (int mt = 0; mt < 3; ++mt) {
            bf16x8 afr = *(const bf16x8*)(Pw + (mt * 16 + col) * 128 + ks * 32 + quad * 8);
#pragma unroll
            for (int nt = 0; nt < 4; ++nt)
                acc[mt][nt] = __builtin_amdgcn_mfma_f32_16x16x32_bf16(
                    afr, bfr[nt], acc[mt][nt], 0, 0, 0);
        }
    }

    // epilogue: elu + store. C/D layout: col=lane&15, row=quad*4+reg.
    float* ob = out + (size_t)bn0 * 12 * 64;
#pragma unroll
    for (int mt = 0; mt < 3; ++mt)
#pragma unroll
        for (int nt = 0; nt < 4; ++nt)
#pragma unroll
            for (int r = 0; r < 4; ++r) {
                const int row = mt * 16 + quad * 4 + r;
                float v = acc[mt][nt][r];
                v = (v > 0.f) ? v : (expf(v) - 1.f);
                ob[row * 64 + nt * 16 + col] = v;
            }
}

extern "C" void kernel_launch(void* const* d_in, const int* in_sizes, int n_in,
                              void* d_out, int out_size, void* d_ws, size_t ws_size,
                              hipStream_t stream) {
    const float* h   = (const float*)d_in[0];   // (16,2048,12,128) fp32
    const int*   adj = (const int*)d_in[1];     // (2,6,6) int32
    const float* W   = (const float*)d_in[2];   // (128,64) fp32
    const float* a   = (const float*)d_in[3];   // (2,128,1) fp32
    float* out = (float*)d_out;                 // (16,2048,12,64) fp32
    float* att_ws = (float*)d_ws;               // 2*2048*36 floats

    hipLaunchKernelGGL(gat_att_kernel, dim3(1024), dim3(256), 0, stream,
                       h, adj, W, a, att_ws);
    // 32768 bn / 4 per wave / 4 waves per block = 2048 blocks
    hipLaunchKernelGGL(gat_main_mfma, dim3(2048), dim3(256), 0, stream,
                       h, W, att_ws, out);
}

// Round 3
// 331.029 us; speedup vs baseline: 1.2038x; 1.0275x over previous
//
#include <hip/hip_runtime.h>
#include <math.h>

#define LRELU_ALPHA 0.2f
#define NEG_BIG -9000000000000000.0f

// d_ws layout (floats): [0,147456) att ; [147456,147968) wa = W@a ;
// [147968, +4096) Wf = bf16 W^T (8192 shorts)
#define WA_OFF 147456
#define WF_OFF 147968

typedef __attribute__((ext_vector_type(8))) short bf16x8;
typedef __attribute__((ext_vector_type(4))) float f32x4;

static __device__ inline unsigned short f2bf(float x) {
    unsigned int u = __float_as_uint(x);
    unsigned int r = (u + 0x7FFFu + ((u >> 16) & 1u)) >> 16;   // RNE
    return (unsigned short)r;
}

// -------------------------------------------------------------------------
// Kernel 0: prep. Blocks 0..31: Wf[n*128+k] = bf16(W[k][n]) (B-frag-ready
// transpose). Block 32: wa[gi*256 + j*128 + c] = sum_f W[c][f]*a[gi,j*64+f].
// -------------------------------------------------------------------------
__global__ __launch_bounds__(256) void gat_prep_kernel(
    const float* __restrict__ W, const float* __restrict__ a,
    float* __restrict__ ws)
{
    const int tid = threadIdx.x;
    if (blockIdx.x < 32) {
        short* wf = (short*)(ws + WF_OFF);
        const int o = blockIdx.x * 256 + tid;
        const int n = o >> 7, k = o & 127;
        wf[o] = (short)f2bf(W[k * 64 + n]);
    } else {
        float* wa = ws + WA_OFF;
        for (int idx = tid; idx < 512; idx += 256) {
            const int gi = idx >> 8, j = (idx >> 7) & 1, c = idx & 127;
            const float* Wr = W + c * 64;
            const float* ar = a + gi * 128 + j * 64;
            float s = 0.f;
#pragma unroll
            for (int f = 0; f < 64; ++f) s = fmaf(Wr[f], ar[f], s);
            wa[idx] = s;
        }
    }
}

// -------------------------------------------------------------------------
// Kernel 1: attention weights via wa trick: s1[q] = h_row_q . wa1.
// One wave per (gi, n). 6 rows x float2/lane, 12 butterfly reductions,
// leaky_relu + adj mask + softmax. No LDS, no 6x64 GEMM.
// -------------------------------------------------------------------------
__global__ __launch_bounds__(256) void gat_att_kernel(
    const float* __restrict__ h, const int* __restrict__ adj,
    float* __restrict__ ws)
{
    const int warp = threadIdx.x >> 6;
    const int lane = threadIdx.x & 63;
    const int iw = blockIdx.x * 4 + warp;   // 0..4095
    const int gi = iw >> 11;
    const int n  = iw & 2047;

    const float* wa = ws + WA_OFF;
    const float2 w1 = *(const float2*)(wa + gi * 256 + 2 * lane);
    const float2 w2 = *(const float2*)(wa + gi * 256 + 128 + 2 * lane);
    const float* hp = h + ((size_t)(gi * 2048 + n) * 12 + (size_t)gi * 6) * 128 + 2 * lane;

    float t1[6], t2[6];
#pragma unroll
    for (int q = 0; q < 6; ++q) {
        const float2 hq = *(const float2*)(hp + q * 128);
        t1[q] = hq.x * w1.x + hq.y * w1.y;
        t2[q] = hq.x * w2.x + hq.y * w2.y;
    }
#pragma unroll
    for (int off = 32; off > 0; off >>= 1) {
#pragma unroll
        for (int q = 0; q < 6; ++q) {
            t1[q] += __shfl_xor(t1[q], off, 64);
            t2[q] += __shfl_xor(t2[q], off, 64);
        }
    }

    if (lane < 6) {
        const int p = lane;
        float s1p = t1[0];
#pragma unroll
        for (int q = 1; q < 6; ++q) { if (p == q) s1p = t1[q]; }

        float row[6];
        float mx = -3.0e38f;
#pragma unroll
        for (int q = 0; q < 6; ++q) {
            float e = s1p + t2[q];
            e = (e > 0.f) ? e : (LRELU_ALPHA * e);
            const int ad = adj[gi * 36 + p * 6 + q];
            const float m = (ad > 0) ? e : NEG_BIG;
            row[q] = m;
            mx = fmaxf(mx, m);
        }
        float sum = 0.f;
#pragma unroll
        for (int q = 0; q < 6; ++q) {
            row[q] = expf(row[q] - mx);
            sum += row[q];
        }
        const float inv = 1.f / sum;
        float* op = ws + (size_t)iw * 36 + p * 6;
#pragma unroll
        for (int q = 0; q < 6; ++q) op[q] = row[q] * inv;
    }
}

// -------------------------------------------------------------------------
// Kernel 2: out = elu( (Att @ h) @ W ) via bf16 MFMA. Barrier-free.
// Wave = 4 (b,n) = 48 rows. Phase 1: fp32 att-combine -> bf16 P in per-wave
// LDS, row stride 136 shorts (conflict-free frag reads). Phase 2: B-frags
// direct from global Wf (L1/L2-hot), 3x4x4 mfma_f32_16x16x32_bf16. Elu store.
// LDS = 52224 B -> 3 blocks/CU.
// -------------------------------------------------------------------------
#define PSTR 136
__global__ __launch_bounds__(256) void gat_main_mfma(
    const float* __restrict__ h, const float* __restrict__ ws,
    float* __restrict__ out)
{
    __shared__ __align__(16) short lds[4 * 48 * PSTR];   // 52224 B
    const int tid  = threadIdx.x;
    const int warp = tid >> 6;
    const int lane = tid & 63;
    short* Pw = lds + warp * 48 * PSTR;

    const int wave_id = blockIdx.x * 4 + warp;
    const int bn0 = wave_id * 4;
    const int half = lane >> 5;
    const int li   = lane & 31;

    // ---- phase 1: P = Att @ h (fp32), pack bf16 into LDS ----
    for (int pair = 0; pair < 2; ++pair) {
        const int bno = pair * 2 + half;
        const int bn  = bn0 + bno;
        const int n   = bn & 2047;

        const float* hb = h + (size_t)bn * 1536 + li * 4;
        float4 hv[12];
#pragma unroll
        for (int r = 0; r < 12; ++r)
            hv[r] = *(const float4*)(hb + r * 128);

#pragma unroll
        for (int gi = 0; gi < 2; ++gi) {
            const float4* ap = (const float4*)(ws + (size_t)(gi * 2048 + n) * 36);
            float attv[36];
#pragma unroll
            for (int j = 0; j < 9; ++j) {
                const float4 av = ap[j];
                attv[j * 4 + 0] = av.x; attv[j * 4 + 1] = av.y;
                attv[j * 4 + 2] = av.z; attv[j * 4 + 3] = av.w;
            }
#pragma unroll
            for (int p = 0; p < 6; ++p) {
                float ax = 0.f, ay = 0.f, az = 0.f, aw = 0.f;
#pragma unroll
                for (int q = 0; q < 6; ++q) {
                    const float apq = attv[p * 6 + q];
                    const float4 hq = hv[gi * 6 + q];
                    ax = fmaf(apq, hq.x, ax);
                    ay = fmaf(apq, hq.y, ay);
                    az = fmaf(apq, hq.z, az);
                    aw = fmaf(apq, hq.w, aw);
                }
                const int row = bno * 12 + gi * 6 + p;
                ushort4 pk;
                pk.x = f2bf(ax); pk.y = f2bf(ay);
                pk.z = f2bf(az); pk.w = f2bf(aw);
                *(ushort4*)(Pw + row * PSTR + li * 4) = pk;
            }
        }
    }
    // no __syncthreads: P is own-wave data; compiler orders via lgkmcnt.

    // ---- phase 2: MFMA against global Wf ----
    const short* wf = (const short*)(ws + WF_OFF);
    const int col  = lane & 15;
    const int quad = lane >> 4;
    f32x4 acc[3][4];
#pragma unroll
    for (int mt = 0; mt < 3; ++mt)
#pragma unroll
        for (int nt = 0; nt < 4; ++nt)
            acc[mt][nt] = (f32x4){0.f, 0.f, 0.f, 0.f};

#pragma unroll
    for (int ks = 0; ks < 4; ++ks) {
        bf16x8 bfr[4];
#pragma unroll
        for (int nt = 0; nt < 4; ++nt)
            bfr[nt] = *(const bf16x8*)(wf + (nt * 16 + col) * 128 + ks * 32 + quad * 8);
        bf16x8 afr[3];
#pragma unroll
        for (int mt = 0; mt < 3; ++mt)
            afr[mt] = *(const bf16x8*)(Pw + (mt * 16 + col) * PSTR + ks * 32 + quad * 8);
#pragma unroll
        for (int mt = 0; mt < 3; ++mt)
#pragma unroll
            for (int nt = 0; nt < 4; ++nt)
                acc[mt][nt] = __builtin_amdgcn_mfma_f32_16x16x32_bf16(
                    afr[mt], bfr[nt], acc[mt][nt], 0, 0, 0);
    }

    // ---- epilogue: elu + store (C/D: col=lane&15, row=quad*4+reg) ----
    float* ob = out + (size_t)bn0 * 768;
#pragma unroll
    for (int mt = 0; mt < 3; ++mt)
#pragma unroll
        for (int nt = 0; nt < 4; ++nt)
#pragma unroll
            for (int r = 0; r < 4; ++r) {
                const int row = mt * 16 + quad * 4 + r;
                float v = acc[mt][nt][r];
                v = (v > 0.f) ? v : (expf(v) - 1.f);
                ob[row * 64 + nt * 16 + col] = v;
            }
}

extern "C" void kernel_launch(void* const* d_in, const int* in_sizes, int n_in,
                              void* d_out, int out_size, void* d_ws, size_t ws_size,
                              hipStream_t stream) {
    const float* h   = (const float*)d_in[0];   // (16,2048,12,128) fp32
    const int*   adj = (const int*)d_in[1];     // (2,6,6) int32
    const float* W   = (const float*)d_in[2];   // (128,64) fp32
    const float* a   = (const float*)d_in[3];   // (2,128,1) fp32
    float* out = (float*)d_out;                 // (16,2048,12,64) fp32
    float* ws  = (float*)d_ws;

    hipLaunchKernelGGL(gat_prep_kernel, dim3(33), dim3(256), 0, stream, W, a, ws);
    hipLaunchKernelGGL(gat_att_kernel, dim3(1024), dim3(256), 0, stream, h, adj, ws);
    hipLaunchKernelGGL(gat_main_mfma, dim3(2048), dim3(256), 0, stream, h, ws, out);
}